// Round 12
// baseline (27.502 us; speedup 1.0000x reference)
//
#include <hip/hip_runtime.h>
#include <math.h>

#define SZ 28

__constant__ int c_fy[10] = {4,4,4,14,14,14,24,24,24,12};
__constant__ int c_fx[10] = {4,14,24,4,14,24,4,14,24,12};

typedef __attribute__((ext_vector_type(4)))  float    f32x4;
typedef __attribute__((ext_vector_type(16))) float    f32x16;
typedef __attribute__((ext_vector_type(8)))  _Float16 f16x8;

// ---------------------------------------------------------------------------
// Prep (R8 version, verified): 49 blocks, one per kstep s; each computes the
// 28-pt DFT table redundantly, threads 0..15 emit the 1 KB w2 slab.
// B-frag for mfma_f32_32x32x16_f16: lane l holds B[k=s*16+(l>>5)*8+j][col=l&31]
// w2[s*512 + ((b*32)+v)*8 + j], b=(k>>3)&1; cols v: 2p=Re(p), 2p+1=Im(p).
// ---------------------------------------------------------------------------
__global__ __launch_bounds__(784) void prep_weights(const float* __restrict__ phase,
                                                    _Float16* __restrict__ w2) {
    __shared__ float tr[SZ][SZ], ti[SZ][SZ];
    __shared__ float g1r[SZ], g1i[SZ];
    const int tid = threadIdx.x;                    // 0..783
    const int s = blockIdx.x;                       // kstep 0..48
    {
        const int t = tid / SZ, k = tid % SZ;
        const int m = (k <= SZ / 2) ? k : SZ - k;
        int num = (14 * k * t - m * m) % 392; if (num < 0) num += 392;
        float sn, cs;
        sincosf((float)num * (6.283185307179586f / 392.0f), &sn, &cs);
        tr[t][k] = cs; ti[t][k] = sn;
    }
    __syncthreads();
    if (tid < SZ) {
        float ar = 0.f, ai = 0.f;
        for (int k = 0; k < SZ; ++k) { ar += tr[tid][k]; ai += ti[tid][k]; }
        g1r[tid] = ar / 28.f; g1i[tid] = ai / 28.f;
    }
    __syncthreads();
    if (tid < 16) {
        const int k = s * 16 + tid;                 // pixel 0..783
        const int y = k / SZ, x = k % SZ;
        float Wv[20];
        float sp, cp; sincosf(phase[k], &sp, &cp);
        #pragma unroll
        for (int p = 0; p < 10; ++p) {
            const int dy = (c_fy[p] - y + SZ) % SZ;
            const int dx = (c_fx[p] - x + SZ) % SZ;
            const float Gr = g1r[dy] * g1r[dx] - g1i[dy] * g1i[dx];
            const float Gi = g1r[dy] * g1i[dx] + g1i[dy] * g1r[dx];
            Wv[p]      = cp * Gr - sp * Gi;          // Re
            Wv[10 + p] = cp * Gi + sp * Gr;          // Im
        }
        const int b = tid >> 3, j = tid & 7;
        #pragma unroll
        for (int v = 0; v < 32; ++v) {
            float val = 0.f;
            if (v < 20) val = (v & 1) ? Wv[10 + (v >> 1)] : Wv[v >> 1];
            w2[s * 512 + (b * 32 + v) * 8 + j] = (_Float16)val;
        }
    }
}

// ---------------------------------------------------------------------------
// Main MFMA GEMM, small-block variant for barrier-domain coverage:
// block = 256 thr = 4 waves (kq = kstep quarter, {2,2,2,1} of 7 per chunk),
// 32 rows/block, grid 1024 -> ~4 independent blocks/CU (vs R11's 2), so one
// block's barrier drain is covered by 3 others' load streams.
// W: each wave's 14 B-fragments live in REGISTERS (loaded once from w2,
// L2-hot; kq==3 pads slot 1 with zero -> static indexing). No W in LDS.
// A: reg-staged f32->f16 (cvt_pkrtz) into fragment-order LDS (lane^s
// swizzle), double-buffered 2x7168, loads 1 chunk ahead.
// Epilogue: 4-way kq reduction (red aliases bufA) + |.|^2.
// ---------------------------------------------------------------------------
__global__ __launch_bounds__(256) void focus_gemm(const float* __restrict__ x,
                                                  const _Float16* __restrict__ w2,
                                                  float* __restrict__ out) {
    __shared__ char smem[14336];                 // 2 x 7168 bufA; alias: red

    const int tid  = threadIdx.x;
    const int lane = tid & 63;
    const int kq = __builtin_amdgcn_readfirstlane(tid >> 6);  // 0..3
    const int row0 = blockIdx.x * 32;

    // ---- B fragments to registers (one-time, coalesced 1KB loads) ----
    f16x8 bfr[14];
    #pragma unroll
    for (int c = 0; c < 7; ++c) {
        bfr[2 * c] = *(const f16x8*)(w2 + (size_t)(c * 7 + 2 * kq) * 512 + lane * 8);
        if (kq < 3) {
            bfr[2 * c + 1] =
                *(const f16x8*)(w2 + (size_t)(c * 7 + 2 * kq + 1) * 512 + lane * 8);
        } else {
            f16x8 z;
            #pragma unroll
            for (int i = 0; i < 8; ++i) z[i] = (_Float16)0.f;
            bfr[2 * c + 1] = z;                  // pad: B=0 -> MFMA no-op
        }
    }

    f32x16 acc;
    #pragma unroll
    for (int i = 0; i < 16; ++i) acc[i] = 0.f;

    // ---- A staging: 896 f4 per chunk (32 rows x 28), 3.5/thread ----
    auto loadA = [&](f32x4* v, int c) {
        const f32x4* x4 = (const f32x4*)x;
        #pragma unroll
        for (int i = 0; i < 4; ++i) {
            const int g = i * 256 + tid;
            if (g < 896) {
                const int r = g / 28, c4 = g % 28;
                v[i] = x4[(size_t)(row0 + r) * 196 + c * 28 + c4];
            }
        }
    };
    auto writeA = [&](const f32x4* v, int c) {
        char* buf = smem + (c & 1) * 7168;
        #pragma unroll
        for (int i = 0; i < 4; ++i) {
            const int g = i * 256 + tid;
            if (g < 896) {
                const int r = g / 28, c4 = g % 28;
                const int s = c4 >> 2, b = (c4 >> 1) & 1;
                const int ln = ((r & 31) + (b << 5)) ^ s;
                auto lo = __builtin_amdgcn_cvt_pkrtz(v[i].x, v[i].y);
                auto hi = __builtin_amdgcn_cvt_pkrtz(v[i].z, v[i].w);
                uint2 d;
                d.x = __builtin_bit_cast(unsigned int, lo);
                d.y = __builtin_bit_cast(unsigned int, hi);
                *(uint2*)(buf + (s * 64 + ln) * 16 + (c4 & 1) * 8) = d;
            }
        }
    };

    f32x4 v[4];
    loadA(v, 0); writeA(v, 0);
    #pragma unroll
    for (int c = 0; c < 7; ++c) {
        __syncthreads();                         // publishes chunk c bufA
        if (c < 6) loadA(v, c + 1);
        {
            char* bA = smem + (c & 1) * 7168;
            #pragma unroll
            for (int sl = 0; sl < 2; ++sl) {
                const int s = (kq == 3) ? 6 : 2 * kq + sl;   // A kstep in chunk
                f16x8 a = *(const f16x8*)(bA + (s * 64 + (lane ^ s)) * 16);
                acc = __builtin_amdgcn_mfma_f32_32x32x16_f16(a, bfr[2 * c + sl],
                                                             acc, 0, 0, 0);
            }
        }
        if (c < 6) writeA(v, c + 1);
    }

    // ---- Epilogue: 4-way kq reduction + |.|^2 (red aliases bufA) ----
    __syncthreads();
    float* red = (float*)smem;                   // [3][64][17] = 13056 B
    if (kq > 0) {
        #pragma unroll
        for (int i = 0; i < 16; ++i)
            red[((kq - 1) * 64 + lane) * 17 + i] = acc[i];
    }
    __syncthreads();
    if (kq == 0) {
        const int col = lane & 31;
        #pragma unroll
        for (int i = 0; i < 16; ++i) {
            const float sum = acc[i]
                + red[(0 * 64 + lane) * 17 + i]
                + red[(1 * 64 + lane) * 17 + i]
                + red[(2 * 64 + lane) * 17 + i];
            const float sq = sum * sum;
            const float tot = sq + __shfl_xor(sq, 1, 64);
            if ((col & 1) == 0 && col < 20) {
                const int r = (i & 3) + 8 * (i >> 2) + 4 * (lane >> 5);
                out[(size_t)(row0 + r) * 10 + (col >> 1)] = tot;
            }
        }
    }
}

extern "C" void kernel_launch(void* const* d_in, const int* in_sizes, int n_in,
                              void* d_out, int out_size, void* d_ws, size_t ws_size,
                              hipStream_t stream) {
    const float* x     = (const float*)d_in[0];   // [32768,1,28,28] f32
    const float* phase = (const float*)d_in[1];   // [28,28] f32
    float* out = (float*)d_out;                   // [32768,10] f32
    _Float16* w2 = (_Float16*)d_ws;               // 49*512 f16 = 50 KB

    hipLaunchKernelGGL(prep_weights, dim3(49), dim3(SZ * SZ), 0, stream, phase, w2);

    const int B = in_sizes[0] / (SZ * SZ);        // 32768
    hipLaunchKernelGGL(focus_gemm, dim3(B / 32), dim3(256), 0, stream, x, w2, out);
}